// Round 1
// baseline (867.455 us; speedup 1.0000x reference)
//
#include <hip/hip_runtime.h>

// Fused 2-layer GRU, persistent-state design.
// S=256 steps, B=8192 batch, IN=1, H=32, L=2.
// Each wave owns 2 batch elements (32 hidden lanes x 2 halves) through all
// timesteps and both layers. Weights stream from LDS (padded rows), h0/h1
// live in registers + wave-private LDS rows for the dot-product broadcasts.

#define S_LEN 256
#define B_SZ  8192
#define H_SZ  32
#define G3    96          // 3*H gate rows
#define WPAD  36          // padded row stride (floats): 144B = 16B aligned, banks spread
#define BPB   16          // batch elements per block
#define NTHR  512         // 8 waves * 64 lanes

#if __has_builtin(__builtin_amdgcn_exp2f)
#define EXP2F(x) __builtin_amdgcn_exp2f(x)
#else
#define EXP2F(x) exp2f(x)
#endif
#if __has_builtin(__builtin_amdgcn_rcpf)
#define RCPF(x) __builtin_amdgcn_rcpf(x)
#else
#define RCPF(x) (1.0f / (x))
#endif

__device__ __forceinline__ float fast_sigmoid(float v) {
    // 1/(1+exp(-v)) ; exp(-v) = exp2(-v*log2e). Saturates correctly at +/-inf.
    return RCPF(1.0f + EXP2F(-1.4426950408889634f * v));
}
__device__ __forceinline__ float fast_tanh(float v) {
    // tanh(v) = 1 - 2/(1+exp(2v)) ; exp(2v) = exp2(v*2*log2e). Saturates to +/-1.
    return 1.0f - 2.0f * RCPF(1.0f + EXP2F(2.8853900817779268f * v));
}
__device__ __forceinline__ float dot4(float4 a, float4 b, float acc) {
    acc = fmaf(a.x, b.x, acc);
    acc = fmaf(a.y, b.y, acc);
    acc = fmaf(a.z, b.z, acc);
    acc = fmaf(a.w, b.w, acc);
    return acc;
}

__global__ __launch_bounds__(NTHR) void gru_fused(
    const float* __restrict__ x,      // (S,B,1)
    const float* __restrict__ h_in,   // (2,B,H)
    const float* __restrict__ W_ih0,  // (96,1)
    const float* __restrict__ W_hh0,  // (96,32)
    const float* __restrict__ b_ih0,  // (96)
    const float* __restrict__ b_hh0,  // (96)
    const float* __restrict__ W_ih1,  // (96,32)
    const float* __restrict__ W_hh1,  // (96,32)
    const float* __restrict__ b_ih1,  // (96)
    const float* __restrict__ b_hh1,  // (96)
    const float* __restrict__ W_out,  // (1,32)
    const float* __restrict__ b_out,  // (1)
    float* __restrict__ out)          // y (S,B,1) then h_state (2,B,H)
{
    __shared__ __align__(16) float sWhh0[G3 * WPAD];
    __shared__ __align__(16) float sWih1[G3 * WPAD];
    __shared__ __align__(16) float sWhh1[G3 * WPAD];
    __shared__ __align__(16) float sh0[BPB][H_SZ];
    __shared__ __align__(16) float sh1[BPB][H_SZ];

    const int tid = threadIdx.x;

    // Cooperative weight staging into padded LDS rows.
    for (int i = tid; i < G3 * H_SZ; i += NTHR) {
        const int r = i >> 5, c = i & 31;
        sWhh0[r * WPAD + c] = W_hh0[i];
        sWih1[r * WPAD + c] = W_ih1[i];
        sWhh1[r * WPAD + c] = W_hh1[i];
    }

    const int wave = tid >> 6;
    const int lane = tid & 63;
    const int j    = lane & 31;   // hidden unit / gate-triple index
    const int half = lane >> 5;   // which of the wave's 2 batch elements
    const int lb   = wave * 2 + half;            // local batch row 0..15
    const int b    = blockIdx.x * BPB + lb;      // global batch index

    // Per-lane scalar parameters (L2/L3-cached broadcast reads).
    const float wi0_r = W_ih0[j];
    const float wi0_z = W_ih0[j + 32];
    const float wi0_n = W_ih0[j + 64];
    const float b0_r  = b_ih0[j]      + b_hh0[j];        // foldable for r,z
    const float b0_z  = b_ih0[j + 32] + b_hh0[j + 32];
    const float bi0_n = b_ih0[j + 64];
    const float bh0_n = b_hh0[j + 64];
    const float b1_r  = b_ih1[j]      + b_hh1[j];
    const float b1_z  = b_ih1[j + 32] + b_hh1[j + 32];
    const float bi1_n = b_ih1[j + 64];
    const float bh1_n = b_hh1[j + 64];
    const float wout  = W_out[j];
    const float bout  = b_out[0];

    // Initial hidden state.
    float h0 = h_in[b * H_SZ + j];
    float h1 = h_in[B_SZ * H_SZ + b * H_SZ + j];
    sh0[lb][j] = h0;
    sh1[lb][j] = h1;
    __syncthreads();   // weights + initial h visible to everyone

    float x_next = x[b];   // x[0*B + b]

#pragma unroll 1
    for (int t = 0; t < S_LEN; ++t) {
        const float x_t = x_next;
        if (t + 1 < S_LEN) x_next = x[(t + 1) * B_SZ + b];

        // ---------------- Layer 0: gh = h0_vec @ W_hh0^T (rows j, j+32, j+64)
        float ar = 0.f, az = 0.f, an = 0.f;
#pragma unroll
        for (int kq = 0; kq < 8; ++kq) {
            const float4 hv = *(const float4*)&sh0[lb][kq * 4];
            const float4 wr = *(const float4*)&sWhh0[j * WPAD + kq * 4];
            const float4 wz = *(const float4*)&sWhh0[(j + 32) * WPAD + kq * 4];
            const float4 wn = *(const float4*)&sWhh0[(j + 64) * WPAD + kq * 4];
            ar = dot4(hv, wr, ar);
            az = dot4(hv, wz, az);
            an = dot4(hv, wn, an);
        }
        const float r0 = fast_sigmoid(fmaf(wi0_r, x_t, ar + b0_r));
        const float z0 = fast_sigmoid(fmaf(wi0_z, x_t, az + b0_z));
        const float n0 = fast_tanh(fmaf(r0, an + bh0_n, fmaf(wi0_n, x_t, bi0_n)));
        const float h0n = fmaf(z0, h0 - n0, n0);   // (1-z)*n + z*h
        h0 = h0n;
        sh0[lb][j] = h0n;   // same-wave write->read; compiler inserts lgkmcnt wait

        // ---------------- Layer 1: gi = h0n_vec @ W_ih1^T, gh = h1_vec @ W_hh1^T
        float br = 0.f, bz = 0.f, bn = 0.f;   // gi accums
        float cr = 0.f, cz = 0.f, cn = 0.f;   // gh accums
#pragma unroll
        for (int kq = 0; kq < 8; ++kq) {
            const float4 h0v = *(const float4*)&sh0[lb][kq * 4];
            const float4 h1v = *(const float4*)&sh1[lb][kq * 4];
            const float4 ur = *(const float4*)&sWih1[j * WPAD + kq * 4];
            const float4 uz = *(const float4*)&sWih1[(j + 32) * WPAD + kq * 4];
            const float4 un = *(const float4*)&sWih1[(j + 64) * WPAD + kq * 4];
            const float4 vr = *(const float4*)&sWhh1[j * WPAD + kq * 4];
            const float4 vz = *(const float4*)&sWhh1[(j + 32) * WPAD + kq * 4];
            const float4 vn = *(const float4*)&sWhh1[(j + 64) * WPAD + kq * 4];
            br = dot4(h0v, ur, br);
            bz = dot4(h0v, uz, bz);
            bn = dot4(h0v, un, bn);
            cr = dot4(h1v, vr, cr);
            cz = dot4(h1v, vz, cz);
            cn = dot4(h1v, vn, cn);
        }
        const float r1 = fast_sigmoid(br + cr + b1_r);
        const float z1 = fast_sigmoid(bz + cz + b1_z);
        const float n1 = fast_tanh(fmaf(r1, cn + bh1_n, bn + bi1_n));
        const float h1n = fmaf(z1, h1 - n1, n1);
        h1 = h1n;
        sh1[lb][j] = h1n;

        // ---------------- Output head: y[t][b] = h1n . W_out + b_out
        float yv = h1n * wout;
        yv += __shfl_xor(yv, 16, 32);
        yv += __shfl_xor(yv, 8, 32);
        yv += __shfl_xor(yv, 4, 32);
        yv += __shfl_xor(yv, 2, 32);
        yv += __shfl_xor(yv, 1, 32);
        if (j == 0) out[t * B_SZ + b] = yv + bout;
    }

    // Final hidden state: out layout = y (S*B) then h_state (2,B,H).
    out[S_LEN * B_SZ + b * H_SZ + j] = h0;
    out[S_LEN * B_SZ + B_SZ * H_SZ + b * H_SZ + j] = h1;
}

extern "C" void kernel_launch(void* const* d_in, const int* in_sizes, int n_in,
                              void* d_out, int out_size, void* d_ws, size_t ws_size,
                              hipStream_t stream) {
    (void)in_sizes; (void)n_in; (void)out_size; (void)d_ws; (void)ws_size;
    const float* x     = (const float*)d_in[0];
    const float* h_in  = (const float*)d_in[1];
    const float* W_ih0 = (const float*)d_in[2];
    const float* W_hh0 = (const float*)d_in[3];
    const float* b_ih0 = (const float*)d_in[4];
    const float* b_hh0 = (const float*)d_in[5];
    const float* W_ih1 = (const float*)d_in[6];
    const float* W_hh1 = (const float*)d_in[7];
    const float* b_ih1 = (const float*)d_in[8];
    const float* b_hh1 = (const float*)d_in[9];
    const float* W_out = (const float*)d_in[10];
    const float* b_out = (const float*)d_in[11];

    dim3 grid(B_SZ / BPB);   // 512 blocks
    dim3 block(NTHR);        // 512 threads = 8 waves
    gru_fused<<<grid, block, 0, stream>>>(x, h_in, W_ih0, W_hh0, b_ih0, b_hh0,
                                          W_ih1, W_hh1, b_ih1, b_hh1,
                                          W_out, b_out, (float*)d_out);
}

// Round 2
// 382.627 us; speedup vs baseline: 2.2671x; 2.2671x over previous
//
#include <hip/hip_runtime.h>

// Fused 2-layer GRU via MFMA, persistent-weight design.
// S=256, B=8192, IN=1, H=32, L=2.
//
// One wave (block=64) owns 16 batch elements for all 256 steps.
// gates[96 x 16batch] = W(A-frag, registers) @ h(B-frag) with
// v_mfma_f32_16x16x32_bf16 (K=32 == H). h carried as hi/lo split bf16
// (rel err ~2^-17); weights bf16-RNE. Biases are pre-folded into the MFMA
// C operand (D != C, so accumulator init is free). The sigmoid/tanh
// exp2-scaling constants are baked into weights+biases at init.
// Per step: 36 MFMA + in-lane epilogue + 2 LDS transposes (D-layout ->
// B-frag) + 1 coalesced y store.

#define S_LEN 256
#define B_SZ  8192
#define H_SZ  32

typedef __attribute__((ext_vector_type(8))) short short8;  // 8 bf16 (4 VGPRs)
typedef __attribute__((ext_vector_type(4))) float f32x4;   // MFMA C/D

#define MFMA(a, b, c) __builtin_amdgcn_mfma_f32_16x16x32_bf16(a, b, c, 0, 0, 0)

#if __has_builtin(__builtin_amdgcn_exp2f)
#define EXP2F(x) __builtin_amdgcn_exp2f(x)
#else
#define EXP2F(x) exp2f(x)
#endif
#if __has_builtin(__builtin_amdgcn_rcpf)
#define RCPF(x) __builtin_amdgcn_rcpf(x)
#else
#define RCPF(x) (1.0f / (x))
#endif

// Pre-scaled activations: input already multiplied by the exp2 constant.
// sigmoid(v) = rcp(1 + exp2(-log2e * v)) ; caller provides p = -log2e*v.
__device__ __forceinline__ float sigm_pre(float p) {
    return RCPF(1.0f + EXP2F(p));
}
// tanh(v) = 1 - 2*rcp(1 + exp2(2*log2e*v)) ; caller provides p = 2*log2e*v.
__device__ __forceinline__ float tanh_pre(float p) {
    return 1.0f - 2.0f * RCPF(1.0f + EXP2F(p));
}

__device__ __forceinline__ short bf_rne(float f) {
    union { float f; unsigned u; } x; x.f = f;
    unsigned u = x.u + 0x7fffu + ((x.u >> 16) & 1u);
    return (short)(u >> 16);
}

// Split 8 fp32 into hi (truncated bf16) + lo (residual bf16). Combined
// representation error ~2^-17 relative.
__device__ __forceinline__ void split8(const float v[8], short8& hi, short8& lo) {
#pragma unroll
    for (int e = 0; e < 8; ++e) {
        union { float f; unsigned u; } x; x.f = v[e];
        unsigned uh = x.u & 0xffff0000u;
        hi[e] = (short)(uh >> 16);
        union { unsigned u; float f; } hf; hf.u = uh;
        union { float f; unsigned u; } l; l.f = v[e] - hf.f;
        lo[e] = (short)(l.u >> 16);
    }
}

__global__ __launch_bounds__(64) void gru_mfma(
    const float* __restrict__ x,      // (S,B,1)
    const float* __restrict__ h_in,   // (2,B,H)
    const float* __restrict__ W_ih0,  // (96,1)
    const float* __restrict__ W_hh0,  // (96,32)
    const float* __restrict__ b_ih0,  // (96)
    const float* __restrict__ b_hh0,  // (96)
    const float* __restrict__ W_ih1,  // (96,32)
    const float* __restrict__ W_hh1,  // (96,32)
    const float* __restrict__ b_ih1,  // (96)
    const float* __restrict__ b_hh1,  // (96)
    const float* __restrict__ W_out,  // (1,32)
    const float* __restrict__ b_out,  // (1)
    float* __restrict__ out)          // y (S*B) then h_state (2,B,H)
{
    // Per-wave transpose buffers, padded stride 36 (2-way banks, free).
    __shared__ __align__(16) float hTa[16 * 36];
    __shared__ __align__(16) float hTb[16 * 36];

    const int lane = threadIdx.x;       // block == 1 wave
    const int n    = lane & 15;         // batch col (B/D frags) & gate row (A frag)
    const int q    = lane >> 4;         // quad
    const int bn   = blockIdx.x * 16 + n;

    const float SRZ = -1.4426950408889634f;  // -log2(e)   (r,z gates: sigmoid)
    const float SN  =  2.8853900817779268f;  // 2*log2(e)  (n gate: tanh)

    // ---- persistent weight A-frags: A[m=lane&15][k=q*8+e], scaled, bf16 ----
    short8 Ahh0[6], Aih1[6], Ahh1[6];
#pragma unroll
    for (int T = 0; T < 6; ++T) {
        const float sc = (T < 4) ? SRZ : SN;
        const int row = T * 16 + n;
        const float* p0 = W_hh0 + row * H_SZ + q * 8;
        const float* p1 = W_ih1 + row * H_SZ + q * 8;
        const float* p2 = W_hh1 + row * H_SZ + q * 8;
#pragma unroll
        for (int e = 0; e < 8; ++e) {
            Ahh0[T][e] = bf_rne(p0[e] * sc);
            Aih1[T][e] = bf_rne(p1[e] * sc);
            Ahh1[T][e] = bf_rne(p2[e] * sc);
        }
    }

    // ---- bias C-inits (fp32, scaled). C/D layout: row = q*4+r, col = n. ----
    f32x4 Cb0[6], Cb1rz[4], Cb1ni[2], Cb1nh[2];
#pragma unroll
    for (int T = 0; T < 6; ++T) {
        const float sc = (T < 4) ? SRZ : SN;
#pragma unroll
        for (int r = 0; r < 4; ++r) {
            const int g = T * 16 + q * 4 + r;
            if (T < 4) {
                Cb0[T][r]   = sc * (b_ih0[g] + b_hh0[g]);
                Cb1rz[T][r] = sc * (b_ih1[g] + b_hh1[g]);
            } else {
                Cb0[T][r]     = sc * b_hh0[g];      // n-gate: b_hh stays in gh
                Cb1ni[T-4][r] = sc * b_ih1[g];
                Cb1nh[T-4][r] = sc * b_hh1[g];
            }
        }
    }

    // ---- layer0 input-weight scalars + head weights (per-lane j = 16T+4q+r) ----
    float wi0r[2][4], wi0z[2][4], wi0n[2][4], bi0n[2][4], woutv[2][4];
#pragma unroll
    for (int T = 0; T < 2; ++T)
#pragma unroll
        for (int r = 0; r < 4; ++r) {
            const int j = T * 16 + q * 4 + r;
            wi0r[T][r] = SRZ * W_ih0[j];
            wi0z[T][r] = SRZ * W_ih0[32 + j];
            wi0n[T][r] = SN  * W_ih0[64 + j];
            bi0n[T][r] = SN  * b_ih0[64 + j];
            woutv[T][r] = W_out[j];
        }
    const float bout = b_out[0];

    // ---- h state: D-layout fp32 + B-frags (hi/lo bf16) ----
    float h0d[2][4], h1d[2][4];
#pragma unroll
    for (int T = 0; T < 2; ++T)
#pragma unroll
        for (int r = 0; r < 4; ++r) {
            const int j = T * 16 + q * 4 + r;
            h0d[T][r] = h_in[bn * H_SZ + j];
            h1d[T][r] = h_in[B_SZ * H_SZ + bn * H_SZ + j];
        }
    short8 B0hi, B0lo, B1hi, B1lo;
    {
        float v[8];
        const float* p = h_in + bn * H_SZ + q * 8;
#pragma unroll
        for (int e = 0; e < 8; ++e) v[e] = p[e];
        split8(v, B0hi, B0lo);
        p += B_SZ * H_SZ;
#pragma unroll
        for (int e = 0; e < 8; ++e) v[e] = p[e];
        split8(v, B1hi, B1lo);
    }

    float xcur = x[bn];

#pragma unroll 1
    for (int t = 0; t < S_LEN; ++t) {
        const float xnext = (t + 1 < S_LEN) ? x[(t + 1) * B_SZ + bn] : 0.0f;

        // ---------- layer 0: gh0 = Whh0 @ h0 (+ folded biases) ----------
        f32x4 g0[6];
#pragma unroll
        for (int T = 0; T < 6; ++T) {
            g0[T] = MFMA(Ahh0[T], B0hi, Cb0[T]);
            g0[T] = MFMA(Ahh0[T], B0lo, g0[T]);
        }
        float h0n_[2][4];
#pragma unroll
        for (int T = 0; T < 2; ++T)
#pragma unroll
            for (int r = 0; r < 4; ++r) {
                const float rg = sigm_pre(fmaf(xcur, wi0r[T][r], g0[T][r]));
                const float zg = sigm_pre(fmaf(xcur, wi0z[T][r], g0[T + 2][r]));
                const float pn = fmaf(xcur, wi0n[T][r], bi0n[T][r]);
                const float ng = tanh_pre(fmaf(rg, g0[T + 4][r], pn));
                const float hv = fmaf(zg, h0d[T][r] - ng, ng);
                h0d[T][r] = hv;
                h0n_[T][r] = hv;
            }
        // transpose h0_new: D-layout -> [n][k] -> B-frag (also next step's B0)
#pragma unroll
        for (int T = 0; T < 2; ++T)
#pragma unroll
            for (int r = 0; r < 4; ++r)
                hTa[n * 36 + T * 16 + q * 4 + r] = h0n_[T][r];
        asm volatile("s_waitcnt lgkmcnt(0)" ::: "memory");
        {
            const float4 ra = *(const float4*)&hTa[n * 36 + q * 8];
            const float4 rb = *(const float4*)&hTa[n * 36 + q * 8 + 4];
            const float v[8] = {ra.x, ra.y, ra.z, ra.w, rb.x, rb.y, rb.z, rb.w};
            split8(v, B0hi, B0lo);
        }

        // ---------- layer 1 ----------
        // r,z tiles: gi and gh merged into one accumulator chain.
        f32x4 grz[4], gin[2], ghn[2];
#pragma unroll
        for (int T = 0; T < 4; ++T) {
            grz[T] = MFMA(Aih1[T], B0hi, Cb1rz[T]);
            grz[T] = MFMA(Aih1[T], B0lo, grz[T]);
            grz[T] = MFMA(Ahh1[T], B1hi, grz[T]);
            grz[T] = MFMA(Ahh1[T], B1lo, grz[T]);
        }
#pragma unroll
        for (int Ti = 0; Ti < 2; ++Ti) {
            gin[Ti] = MFMA(Aih1[Ti + 4], B0hi, Cb1ni[Ti]);
            gin[Ti] = MFMA(Aih1[Ti + 4], B0lo, gin[Ti]);
            ghn[Ti] = MFMA(Ahh1[Ti + 4], B1hi, Cb1nh[Ti]);
            ghn[Ti] = MFMA(Ahh1[Ti + 4], B1lo, ghn[Ti]);
        }
        float ysum = 0.0f;
        float h1n_[2][4];
#pragma unroll
        for (int T = 0; T < 2; ++T)
#pragma unroll
            for (int r = 0; r < 4; ++r) {
                const float rg = sigm_pre(grz[T][r]);
                const float zg = sigm_pre(grz[T + 2][r]);
                const float ng = tanh_pre(fmaf(rg, ghn[T][r], gin[T][r]));
                const float hv = fmaf(zg, h1d[T][r] - ng, ng);
                h1d[T][r] = hv;
                h1n_[T][r] = hv;
                ysum = fmaf(hv, woutv[T][r], ysum);
            }
        // y: reduce over quads (hidden dim), lanes 0..15 store 16 batch (64 B).
        ysum += __shfl_xor(ysum, 16);
        ysum += __shfl_xor(ysum, 32);
        if (lane < 16) out[t * B_SZ + bn] = ysum + bout;

        // transpose h1_new -> next step's B1 frags
#pragma unroll
        for (int T = 0; T < 2; ++T)
#pragma unroll
            for (int r = 0; r < 4; ++r)
                hTb[n * 36 + T * 16 + q * 4 + r] = h1n_[T][r];
        asm volatile("s_waitcnt lgkmcnt(0)" ::: "memory");
        {
            const float4 ra = *(const float4*)&hTb[n * 36 + q * 8];
            const float4 rb = *(const float4*)&hTb[n * 36 + q * 8 + 4];
            const float v[8] = {ra.x, ra.y, ra.z, ra.w, rb.x, rb.y, rb.z, rb.w};
            split8(v, B1hi, B1lo);
        }

        xcur = xnext;
    }

    // final h_state: out[y] ++ h0 ++ h1
#pragma unroll
    for (int T = 0; T < 2; ++T)
#pragma unroll
        for (int r = 0; r < 4; ++r) {
            const int j = T * 16 + q * 4 + r;
            out[S_LEN * B_SZ + bn * H_SZ + j] = h0d[T][r];
            out[S_LEN * B_SZ + B_SZ * H_SZ + bn * H_SZ + j] = h1d[T][r];
        }
}

extern "C" void kernel_launch(void* const* d_in, const int* in_sizes, int n_in,
                              void* d_out, int out_size, void* d_ws, size_t ws_size,
                              hipStream_t stream) {
    (void)in_sizes; (void)n_in; (void)out_size; (void)d_ws; (void)ws_size;
    const float* x     = (const float*)d_in[0];
    const float* h_in  = (const float*)d_in[1];
    const float* W_ih0 = (const float*)d_in[2];
    const float* W_hh0 = (const float*)d_in[3];
    const float* b_ih0 = (const float*)d_in[4];
    const float* b_hh0 = (const float*)d_in[5];
    const float* W_ih1 = (const float*)d_in[6];
    const float* W_hh1 = (const float*)d_in[7];
    const float* b_ih1 = (const float*)d_in[8];
    const float* b_hh1 = (const float*)d_in[9];
    const float* W_out = (const float*)d_in[10];
    const float* b_out = (const float*)d_in[11];

    dim3 grid(B_SZ / 16);   // 512 waves, one per block
    dim3 block(64);
    gru_mfma<<<grid, block, 0, stream>>>(x, h_in, W_ih0, W_hh0, b_ih0, b_hh0,
                                         W_ih1, W_hh1, b_ih1, b_hh1,
                                         W_out, b_out, (float*)d_out);
}